// Round 8
// baseline (446.025 us; speedup 1.0000x reference)
//
#include <hip/hip_runtime.h>

#define D 128
#define BSHIFT 10
#define BSIZE 1024       // nodes per bucket
#define NBMAX 128        // max buckets (N <= 131072)
#define CHUNK 4096       // edges per block in bucketing kernels
#define SRCBITS 17
#define SRCMASK 0x1FFFF
#define AST 136          // LDS A-tile row stride (u16) — breaks bank conflicts

typedef unsigned int uint;
typedef unsigned short u16;
typedef __attribute__((ext_vector_type(8))) short short8;
typedef __attribute__((ext_vector_type(4))) float floatx4;

// ---- bf16 helpers (RNE) ----
__device__ __forceinline__ u16 f2bf(float f) {
    union { float f; uint u; } c; c.f = f;
    uint u = c.u;
    u += 0x7FFFu + ((u >> 16) & 1u);
    return (u16)(u >> 16);
}
__device__ __forceinline__ float bflo(uint u) {
    union { uint u; float f; } c; c.u = u << 16; return c.f;
}
__device__ __forceinline__ float bfhi(uint u) {
    union { uint u; float f; } c; c.u = u & 0xFFFF0000u; return c.f;
}

// ------- pass 1: coarse bucket histograms for BOTH dst and src (LDS only) --
__global__ __launch_bounds__(256) void hist2_kernel(
    const int* __restrict__ src, const int* __restrict__ dst,
    int* __restrict__ cnt_d, int* __restrict__ cnt_s, int E)
{
    __shared__ int ld[NBMAX];
    __shared__ int ls[NBMAX];
    int t = threadIdx.x;
    if (t < NBMAX) { ld[t] = 0; ls[t] = 0; }
    __syncthreads();
    int base = blockIdx.x * CHUNK;
    int end  = min(base + CHUNK, E);
    for (int i = base + t; i < end; i += 256) {
        atomicAdd(&ld[dst[i] >> BSHIFT], 1);
        atomicAdd(&ls[src[i] >> BSHIFT], 1);
    }
    __syncthreads();
    if (t < NBMAX) {
        if (ld[t]) atomicAdd(&cnt_d[t], ld[t]);
        if (ls[t]) atomicAdd(&cnt_s[t], ls[t]);
    }
}

// ------- scan both bucket-count arrays (single block) ----------------------
__global__ __launch_bounds__(NBMAX) void scan2_kernel(
    const int* __restrict__ cnt_d, const int* __restrict__ cnt_s,
    int* __restrict__ ptr_d, int* __restrict__ cur_d,
    int* __restrict__ ptr_s, int* __restrict__ cur_s,
    int* __restrict__ row_ptr, int NB, int N, int E)
{
    __shared__ int sh[NBMAX];
    int t = threadIdx.x;
    // dst buckets
    sh[t] = (t < NB) ? cnt_d[t] : 0;
    __syncthreads();
    for (int off = 1; off < NBMAX; off <<= 1) {
        int v = (t >= off) ? sh[t - off] : 0;
        __syncthreads();
        sh[t] += v;
        __syncthreads();
    }
    {
        int excl = (t == 0) ? 0 : sh[t - 1];
        if (t < NB) { ptr_d[t] = excl; cur_d[t] = excl; }
        if (t == 0) ptr_d[NB] = E;
    }
    __syncthreads();
    // src buckets
    sh[t] = (t < NB) ? cnt_s[t] : 0;
    __syncthreads();
    for (int off = 1; off < NBMAX; off <<= 1) {
        int v = (t >= off) ? sh[t - off] : 0;
        __syncthreads();
        sh[t] += v;
        __syncthreads();
    }
    {
        int excl = (t == 0) ? 0 : sh[t - 1];
        if (t < NB) { ptr_s[t] = excl; cur_s[t] = excl; }
        if (t == 0) { ptr_s[NB] = E; row_ptr[N] = E; }
    }
}

// ------- pass 2: scatter into dst buckets (packed) and src buckets (local) -
__global__ __launch_bounds__(256) void scatter2_kernel(
    const int* __restrict__ src, const int* __restrict__ dst,
    int* __restrict__ cur_d, int* __restrict__ cur_s,
    int* __restrict__ dpacked, u16* __restrict__ spacked, int E)
{
    __shared__ int lcd[NBMAX], lbd[NBMAX], lcs[NBMAX], lbs[NBMAX];
    __shared__ int dbuf[CHUNK];
    __shared__ int sbuf[CHUNK];
    int t = threadIdx.x;
    if (t < NBMAX) { lcd[t] = 0; lcs[t] = 0; }
    __syncthreads();
    int base = blockIdx.x * CHUNK;
    int end  = min(base + CHUNK, E);
    for (int i = base + t; i < end; i += 256) {
        int d = dst[i], s = src[i];
        dbuf[i - base] = d; sbuf[i - base] = s;
        atomicAdd(&lcd[d >> BSHIFT], 1);
        atomicAdd(&lcs[s >> BSHIFT], 1);
    }
    __syncthreads();
    if (t < NBMAX) {
        int c = lcd[t];
        lbd[t] = c ? atomicAdd(&cur_d[t], c) : 0;
        lcd[t] = 0;
        int cs = lcs[t];
        lbs[t] = cs ? atomicAdd(&cur_s[t], cs) : 0;
        lcs[t] = 0;
    }
    __syncthreads();
    for (int i = base + t; i < end; i += 256) {
        int d = dbuf[i - base], s = sbuf[i - base];
        int bd = d >> BSHIFT;
        int slot = lbd[bd] + atomicAdd(&lcd[bd], 1);
        dpacked[slot] = ((d & (BSIZE - 1)) << SRCBITS) | s;
        int bs = s >> BSHIFT;
        int slot2 = lbs[bs] + atomicAdd(&lcs[bs], 1);
        spacked[slot2] = (u16)(s & (BSIZE - 1));
    }
}

// ------- per-dst-bucket fine CSR: row_ptr, norm_dst, col -------------------
__global__ __launch_bounds__(1024) void fine_place_kernel(
    const int* __restrict__ dpacked, const int* __restrict__ ptr_d,
    int* __restrict__ row_ptr, float* __restrict__ norm_dst,
    int* __restrict__ col, int N)
{
    __shared__ int lcnt[BSIZE];
    __shared__ int lptr[BSIZE];
    int b = blockIdx.x, t = threadIdx.x;
    int nbase = b << BSHIFT;
    int beg = ptr_d[b], end = ptr_d[b + 1];
    lcnt[t] = 0;
    __syncthreads();
    for (int i = beg + t; i < end; i += 1024)
        atomicAdd(&lcnt[dpacked[i] >> SRCBITS], 1);
    __syncthreads();
    for (int off = 1; off < BSIZE; off <<= 1) {
        int v = (t >= off) ? lcnt[t - off] : 0;
        __syncthreads();
        lcnt[t] += v;
        __syncthreads();
    }
    {
        int incl = lcnt[t];
        int excl = (t == 0) ? 0 : lcnt[t - 1];
        int node = nbase + t;
        if (node < N) {
            row_ptr[node] = beg + excl;
            norm_dst[node] = rsqrtf((float)max(incl - excl, 1));
        }
        lptr[t] = beg + excl;
    }
    __syncthreads();
    for (int i = beg + t; i < end; i += 1024) {
        int p = dpacked[i];
        int slot = atomicAdd(&lptr[p >> SRCBITS], 1);
        col[slot] = p & SRCMASK;
    }
}

// ------- per-src-bucket LDS histogram -> norm_src --------------------------
__global__ __launch_bounds__(1024) void fine_count_src_kernel(
    const u16* __restrict__ spacked, const int* __restrict__ ptr_s,
    float* __restrict__ norm_src, int N)
{
    __shared__ int lcnt[BSIZE];
    int b = blockIdx.x, t = threadIdx.x;
    int beg = ptr_s[b], end = ptr_s[b + 1];
    lcnt[t] = 0;
    __syncthreads();
    for (int i = beg + t; i < end; i += 1024)
        atomicAdd(&lcnt[spacked[i]], 1);
    __syncthreads();
    int node = (b << BSHIFT) + t;
    if (node < N) norm_src[node] = rsqrtf((float)max(lcnt[t], 1));
}

// ------- fp32 -> bf16 (RNE), float4 -> ushort4 -----------------------------
__global__ __launch_bounds__(256) void convert_bf16_kernel(
    const float* __restrict__ x, u16* __restrict__ y, int total4)
{
    int i = blockIdx.x * 256 + threadIdx.x;
    if (i >= total4) return;
    float4 v = ((const float4*)x)[i];
    ushort4 o;
    o.x = f2bf(v.x); o.y = f2bf(v.y); o.z = f2bf(v.z); o.w = f2bf(v.w);
    ((ushort4*)y)[i] = o;
}

// ------- W [k][n] fp32 -> W_T [n][k] bf16 ----------------------------------
__global__ __launch_bounds__(256) void convert_wT_kernel(
    const float* __restrict__ W, u16* __restrict__ WT)
{
    int i = blockIdx.x * 256 + threadIdx.x;   // i = k*128 + n
    int k = i >> 7, n = i & 127;
    WT[n * 128 + k] = f2bf(W[i]);
}

// ---------------- fused aggregate + MFMA GEMM ------------------------------
// Block = 256 thr, 64 nodes. Phase 1: wave-per-node gather-aggregate into
// LDS bf16 tile (stride AST breaks bank conflicts). Phase 2: each wave MFMAs
// its 16-row strip: out = relu((norm_dst * A^ hs_norm) @ W + b).
template <bool BF16_OUT>
__global__ __launch_bounds__(256) void agg_gemm_kernel(
    const u16* __restrict__ hs, const int* __restrict__ row_ptr,
    const int* __restrict__ col, const float* __restrict__ norm_src,
    const float* __restrict__ norm_dst, const u16* __restrict__ WT,
    const float* __restrict__ bias, float* __restrict__ out_f,
    u16* __restrict__ out_b, int N)
{
    __shared__ u16 aT[64 * AST];   // 17.4 KB
    int wave = threadIdx.x >> 6;
    int lane = threadIdx.x & 63;
    int g = lane >> 4;         // edge-group / quad
    int l16 = lane & 15;       // row-in-frag / feature-slot
    int base = blockIdx.x * 64;
    const uint4* h4 = (const uint4*)hs;

    // ---- phase 1: aggregate 16 nodes per wave ----
    for (int it = 0; it < 16; ++it) {
        int ln = (it << 2) + wave;
        int n = base + ln;
        float acc[8];
        #pragma unroll
        for (int j = 0; j < 8; ++j) acc[j] = 0.f;
        if (n < N) {
            int beg = row_ptr[n], end = row_ptr[n + 1];
            int i = beg + g;
            for (; i + 4 < end; i += 8) {
                int s0 = col[i], s1 = col[i + 4];
                float ns0 = norm_src[s0], ns1 = norm_src[s1];
                uint4 v0 = h4[(size_t)s0 * 16 + l16];
                uint4 v1 = h4[(size_t)s1 * 16 + l16];
                acc[0] = fmaf(bflo(v0.x), ns0, acc[0]);
                acc[1] = fmaf(bfhi(v0.x), ns0, acc[1]);
                acc[2] = fmaf(bflo(v0.y), ns0, acc[2]);
                acc[3] = fmaf(bfhi(v0.y), ns0, acc[3]);
                acc[4] = fmaf(bflo(v0.z), ns0, acc[4]);
                acc[5] = fmaf(bfhi(v0.z), ns0, acc[5]);
                acc[6] = fmaf(bflo(v0.w), ns0, acc[6]);
                acc[7] = fmaf(bfhi(v0.w), ns0, acc[7]);
                acc[0] = fmaf(bflo(v1.x), ns1, acc[0]);
                acc[1] = fmaf(bfhi(v1.x), ns1, acc[1]);
                acc[2] = fmaf(bflo(v1.y), ns1, acc[2]);
                acc[3] = fmaf(bfhi(v1.y), ns1, acc[3]);
                acc[4] = fmaf(bflo(v1.z), ns1, acc[4]);
                acc[5] = fmaf(bfhi(v1.z), ns1, acc[5]);
                acc[6] = fmaf(bflo(v1.w), ns1, acc[6]);
                acc[7] = fmaf(bfhi(v1.w), ns1, acc[7]);
            }
            if (i < end) {
                int s = col[i];
                float ns = norm_src[s];
                uint4 v = h4[(size_t)s * 16 + l16];
                acc[0] = fmaf(bflo(v.x), ns, acc[0]);
                acc[1] = fmaf(bfhi(v.x), ns, acc[1]);
                acc[2] = fmaf(bflo(v.y), ns, acc[2]);
                acc[3] = fmaf(bfhi(v.y), ns, acc[3]);
                acc[4] = fmaf(bflo(v.z), ns, acc[4]);
                acc[5] = fmaf(bfhi(v.z), ns, acc[5]);
                acc[6] = fmaf(bflo(v.w), ns, acc[6]);
                acc[7] = fmaf(bfhi(v.w), ns, acc[7]);
            }
        }
        #pragma unroll
        for (int j = 0; j < 8; ++j) {
            acc[j] += __shfl_xor(acc[j], 16, 64);
            acc[j] += __shfl_xor(acc[j], 32, 64);
        }
        if (g == 0) {
            float nd = (n < N) ? norm_dst[n] : 0.f;
            ushort4 lo, hi;
            lo.x = f2bf(acc[0] * nd); lo.y = f2bf(acc[1] * nd);
            lo.z = f2bf(acc[2] * nd); lo.w = f2bf(acc[3] * nd);
            hi.x = f2bf(acc[4] * nd); hi.y = f2bf(acc[5] * nd);
            hi.z = f2bf(acc[6] * nd); hi.w = f2bf(acc[7] * nd);
            ushort4* o = (ushort4*)(aT + ln * AST + l16 * 8);
            o[0] = lo; o[1] = hi;
        }
    }
    __syncthreads();

    // ---- phase 2: MFMA on 16-row strip ----
    const u16* Arow = aT + (wave * 16 + l16) * AST;
    floatx4 acc[8];
    #pragma unroll
    for (int c = 0; c < 8; ++c) acc[c] = (floatx4){0.f, 0.f, 0.f, 0.f};

    #pragma unroll
    for (int q = 0; q < 4; ++q) {
        short8 a = *(const short8*)(Arow + q * 32 + g * 8);
        #pragma unroll
        for (int c = 0; c < 8; ++c) {
            short8 b = *(const short8*)(WT + (size_t)(c * 16 + l16) * D + q * 32 + g * 8);
            acc[c] = __builtin_amdgcn_mfma_f32_16x16x32_bf16(a, b, acc[c], 0, 0, 0);
        }
    }

    int row_base = base + wave * 16;
    #pragma unroll
    for (int c = 0; c < 8; ++c) {
        int colc = c * 16 + l16;
        float bv = bias[colc];
        #pragma unroll
        for (int r = 0; r < 4; ++r) {
            int row = row_base + g * 4 + r;
            if (row < N) {
                float v = fmaxf(acc[c][r] + bv, 0.f);
                if (BF16_OUT) out_b[(size_t)row * D + colc] = f2bf(v);
                else          out_f[(size_t)row * D + colc] = v;
            }
        }
    }
}

extern "C" void kernel_launch(void* const* d_in, const int* in_sizes, int n_in,
                              void* d_out, int out_size, void* d_ws, size_t ws_size,
                              hipStream_t stream)
{
    const float* features = (const float*)d_in[0];
    const int*   src      = (const int*)d_in[1];
    const int*   dst      = (const int*)d_in[2];
    const float* W1       = (const float*)d_in[3];
    const float* b1       = (const float*)d_in[4];
    const float* W2       = (const float*)d_in[5];
    const float* b2       = (const float*)d_in[6];
    float*       out      = (float*)d_out;

    const int N = in_sizes[0] / D;
    const int E = in_sizes[1];
    const int NB = (N + BSIZE - 1) >> BSHIFT;

    // workspace (bump-allocated, 256-B aligned)
    char* p = (char*)d_ws;
    auto alloc = [&](size_t bytes) {
        char* r = p; p += (bytes + 255) & ~(size_t)255; return r;
    };
    float* norm_src = (float*)alloc((size_t)N * 4);
    float* norm_dst = (float*)alloc((size_t)N * 4);
    int*   row_ptr  = (int*)alloc(((size_t)N + 1) * 4);
    int*   col      = (int*)alloc((size_t)E * 4);
    int*   dpacked  = (int*)alloc((size_t)E * 4);
    u16*   spacked  = (u16*)alloc((size_t)E * 2);
    int*   cnt_d    = (int*)alloc(NBMAX * 4);
    int*   cnt_s    = (int*)alloc(NBMAX * 4);
    int*   ptr_d    = (int*)alloc((NBMAX + 1) * 4);
    int*   ptr_s    = (int*)alloc((NBMAX + 1) * 4);
    int*   cur_d    = (int*)alloc(NBMAX * 4);
    int*   cur_s    = (int*)alloc(NBMAX * 4);
    u16*   feat_bf  = (u16*)alloc((size_t)N * D * 2);
    u16*   hs_bf    = (u16*)alloc((size_t)N * D * 2);
    u16*   wT1      = (u16*)alloc(D * D * 2);
    u16*   wT2      = (u16*)alloc(D * D * 2);

    const int ebk = (E + CHUNK - 1) / CHUNK;
    const int fused_blocks = (N + 63) / 64;
    const int cv_blocks = (N * 32 + 255) / 256;
    const int wt_blocks = (D * D + 255) / 256;

    // ---- CSR build: no per-edge global atomics anywhere ----
    hipMemsetAsync(cnt_d, 0, 2 * NBMAX * sizeof(int), stream);  // cnt_d + cnt_s adjacent
    hist2_kernel<<<ebk, 256, 0, stream>>>(src, dst, cnt_d, cnt_s, E);
    scan2_kernel<<<1, NBMAX, 0, stream>>>(cnt_d, cnt_s, ptr_d, cur_d, ptr_s, cur_s, row_ptr, NB, N, E);
    scatter2_kernel<<<ebk, 256, 0, stream>>>(src, dst, cur_d, cur_s, dpacked, spacked, E);
    fine_place_kernel<<<NB, 1024, 0, stream>>>(dpacked, ptr_d, row_ptr, norm_dst, col, N);
    fine_count_src_kernel<<<NB, 1024, 0, stream>>>(spacked, ptr_s, norm_src, N);
    convert_bf16_kernel<<<cv_blocks, 256, 0, stream>>>(features, feat_bf, N * 32);
    convert_wT_kernel<<<wt_blocks, 256, 0, stream>>>(W1, wT1);
    convert_wT_kernel<<<wt_blocks, 256, 0, stream>>>(W2, wT2);

    // ---- fused layers ----
    agg_gemm_kernel<true><<<fused_blocks, 256, 0, stream>>>(
        feat_bf, row_ptr, col, norm_src, norm_dst, wT1, b1, nullptr, hs_bf, N);
    agg_gemm_kernel<false><<<fused_blocks, 256, 0, stream>>>(
        hs_bf, row_ptr, col, norm_src, norm_dst, wT2, b2, out, nullptr, N);
}